// Round 2
// baseline (512.144 us; speedup 1.0000x reference)
//
#include <hip/hip_runtime.h>
#include <hip/hip_bf16.h>

using bf16 = __hip_bfloat16;

#define B_   2
#define L_   1024
#define DIN  512
#define DM   1024
#define DS   16
#define DD   64
#define KER_ 4
#define NROW (B_*L_)     // 2048
#define LC   64          // scan chunk length
#define NC   (L_/LC)     // 16 chunks

__device__ __forceinline__ float tof(bf16 v){ return __bfloat162float(v); }
__device__ __forceinline__ float tof(float v){ return v; }
__device__ __forceinline__ void stf(float* p, float v){ *p = v; }
__device__ __forceinline__ void stf(bf16* p, float v){ *p = __float2bfloat16(v); }
__device__ __forceinline__ float silu_f(float v){ return v / (1.f + expf(-v)); }

// ---------------------------------------------------------------------------
// Generic NT GEMM: C[M,N] = A[M,K] * B[N,K]^T, row-major, fp32 accumulate.
// 64x64 tile, 16x16 threads, 4x4 per thread. All dims multiples of 64/16.
// ---------------------------------------------------------------------------
template<typename TA, typename TB, typename TC>
__global__ __launch_bounds__(256)
void gemm_nt(const TA* __restrict__ A, const TB* __restrict__ B, TC* __restrict__ C,
             int M, int N, int K) {
  __shared__ float As[16][65];
  __shared__ float Bs[16][65];
  const int m0 = blockIdx.y * 64;
  const int n0 = blockIdx.x * 64;
  const int tx = threadIdx.x, ty = threadIdx.y;
  const int tid = ty * 16 + tx;
  float acc[4][4] = {{0.f}};
  for (int k0 = 0; k0 < K; k0 += 16) {
#pragma unroll
    for (int i = 0; i < 4; i++) {
      int idx = tid + i * 256;            // 0..1023
      int mi = idx >> 4, ki = idx & 15;
      As[ki][mi] = tof(A[(m0 + mi) * K + k0 + ki]);
      Bs[ki][mi] = tof(B[(n0 + mi) * K + k0 + ki]);
    }
    __syncthreads();
#pragma unroll
    for (int k = 0; k < 16; k++) {
      float av[4], bv[4];
#pragma unroll
      for (int i = 0; i < 4; i++) av[i] = As[k][ty * 4 + i];
#pragma unroll
      for (int j = 0; j < 4; j++) bv[j] = Bs[k][tx * 4 + j];
#pragma unroll
      for (int i = 0; i < 4; i++)
#pragma unroll
        for (int j = 0; j < 4; j++)
          acc[i][j] += av[i] * bv[j];
    }
    __syncthreads();
  }
#pragma unroll
  for (int i = 0; i < 4; i++)
#pragma unroll
    for (int j = 0; j < 4; j++)
      stf(&C[(m0 + ty * 4 + i) * N + n0 + tx * 4 + j], acc[i][j]);
}

// ---------------------------------------------------------------------------
// Depthwise causal conv (KER=4) + bias + silu on first half of ab -> x
// ---------------------------------------------------------------------------
__global__ __launch_bounds__(256)
void conv_silu_k(const float* __restrict__ ab, const float* __restrict__ cw,
                 const float* __restrict__ cb, float* __restrict__ x) {
  int idx = blockIdx.x * 256 + threadIdx.x;   // n*DM + d
  int d  = idx & (DM - 1);
  int n  = idx >> 10;
  int l  = n & (L_ - 1);
  int bb = n >> 10;
  float acc = cb[d];
#pragma unroll
  for (int k = 0; k < KER_; k++) {
    int ll = l - (KER_ - 1) + k;
    if (ll >= 0) acc += ab[(bb * L_ + ll) * (2 * DM) + d] * cw[d * KER_ + k];
  }
  x[idx] = silu_f(acc);
}

// ---------------------------------------------------------------------------
// Bm (16), Cm (16), t1 (64) projections of x row n. One block per row.
// ---------------------------------------------------------------------------
__global__ __launch_bounds__(128)
void proj96_k(const float* __restrict__ x, const float* __restrict__ WB,
              const float* __restrict__ WC, const float* __restrict__ WD1,
              float* __restrict__ Bm, float* __restrict__ Cm, float* __restrict__ t1) {
  __shared__ float xs[DM];
  int n = blockIdx.x;
  for (int i = threadIdx.x; i < DM; i += 128) xs[i] = x[n * DM + i];
  __syncthreads();
  int j = threadIdx.x;
  if (j >= 96) return;
  const float* w = (j < 16) ? (WB + j * DM)
                 : (j < 32) ? (WC + (j - 16) * DM)
                            : (WD1 + (j - 32) * DM);
  float acc = 0.f;
#pragma unroll 8
  for (int k = 0; k < DM; k++) acc += xs[k] * w[k];
  if (j < 16)      Bm[n * DS + j] = acc;
  else if (j < 32) Cm[n * DS + (j - 16)] = acc;
  else             t1[n * DD + (j - 32)] = acc;
}

// ---------------------------------------------------------------------------
// delta[n,d] = softplus(D[d] + t1[n,:] . W_D2[d,:])
// ---------------------------------------------------------------------------
__global__ __launch_bounds__(256)
void delta_k(const float* __restrict__ t1, const float* __restrict__ WD2,
             const float* __restrict__ Dv, float* __restrict__ delta) {
  __shared__ float ts[DD];
  int n = blockIdx.x;
  int d = blockIdx.y * 256 + threadIdx.x;
  if (threadIdx.x < DD) ts[threadIdx.x] = t1[n * DD + threadIdx.x];
  __syncthreads();
  float acc = Dv[d];
#pragma unroll
  for (int e = 0; e < DD; e++) acc += ts[e] * WD2[d * DD + e];
  delta[n * DM + d] = fmaxf(acc, 0.f) + log1pf(expf(-fabsf(acc)));   // stable softplus
}

// ---------------------------------------------------------------------------
// Scan pass 1: per (b, chunk, d) compute local scan carry (prodA[s], h_end[s])
// h recurrence: h[s] = (e[s]*delta)*h[s] + Bm[s]*delta*x
// ---------------------------------------------------------------------------
__global__ __launch_bounds__(256)
void scan1_k(const float* __restrict__ x, const float* __restrict__ delta,
             const float* __restrict__ Bm, const float* __restrict__ A,
             float* __restrict__ hc, float* __restrict__ ap) {
  int t  = blockIdx.x * 256 + threadIdx.x;   // ((b*NC + c)*DM + d)
  int d  = t & (DM - 1);
  int bc = t >> 10;
  int c  = bc & (NC - 1);
  int b  = bc >> 4;
  float e[DS], h[DS], p[DS];
#pragma unroll
  for (int s = 0; s < DS; s++) { e[s] = expf(-A[d * DS + s]); h[s] = 0.f; p[s] = 1.f; }
  int nbase = b * L_ + c * LC;
  for (int i = 0; i < LC; i++) {
    int n = nbase + i;
    float dl = delta[n * DM + d];
    float xv = x[n * DM + d];
    float dx = dl * xv;
#pragma unroll
    for (int s = 0; s < DS; s++) {
      float a_ = e[s] * dl;
      h[s] = a_ * h[s] + Bm[n * DS + s] * dx;
      p[s] *= a_;
    }
  }
#pragma unroll
  for (int s = 0; s < DS; s++) { hc[t * DS + s] = h[s]; ap[t * DS + s] = p[s]; }
}

// ---------------------------------------------------------------------------
// Combine chunk carries sequentially over the NC=16 chunks -> initial h per chunk
// ---------------------------------------------------------------------------
__global__ __launch_bounds__(256)
void scomb_k(const float* __restrict__ hc, const float* __restrict__ ap,
             float* __restrict__ hinit) {
  int t  = blockIdx.x * 256 + threadIdx.x;   // (b*DM + d)*DS + s
  int s  = t & (DS - 1);
  int bd = t >> 4;
  int d  = bd & (DM - 1);
  int b  = bd >> 10;
  float H = 0.f;
  for (int c = 0; c < NC; c++) {
    int idx = ((b * NC + c) * DM + d) * DS + s;
    hinit[idx] = H;
    H = ap[idx] * H + hc[idx];
  }
}

// ---------------------------------------------------------------------------
// Scan pass 2: replay each chunk from hinit, y = sum_s h*Cm + D*x, * silu(gate)
// ---------------------------------------------------------------------------
__global__ __launch_bounds__(256)
void scan2_k(const float* __restrict__ x, const float* __restrict__ delta,
             const float* __restrict__ Bm, const float* __restrict__ Cm,
             const float* __restrict__ hinit, const float* __restrict__ ab,
             const float* __restrict__ A, const float* __restrict__ Dv,
             float* __restrict__ sout) {
  int t  = blockIdx.x * 256 + threadIdx.x;
  int d  = t & (DM - 1);
  int bc = t >> 10;
  int c  = bc & (NC - 1);
  int b  = bc >> 4;
  float e[DS], h[DS];
#pragma unroll
  for (int s = 0; s < DS; s++) { e[s] = expf(-A[d * DS + s]); h[s] = hinit[t * DS + s]; }
  float Dd = Dv[d];
  int nbase = b * L_ + c * LC;
  for (int i = 0; i < LC; i++) {
    int n = nbase + i;
    float dl = delta[n * DM + d];
    float xv = x[n * DM + d];
    float dx = dl * xv;
    float y = 0.f;
#pragma unroll
    for (int s = 0; s < DS; s++) {
      h[s] = e[s] * dl * h[s] + Bm[n * DS + s] * dx;
      y += h[s] * Cm[n * DS + s];
    }
    y += Dd * xv;
    float g = ab[n * (2 * DM) + DM + d];
    sout[n * DM + d] = y * silu_f(g);
  }
}

// ---------------------------------------------------------------------------
extern "C" void kernel_launch(void* const* d_in, const int* in_sizes, int n_in,
                              void* d_out, int out_size, void* d_ws, size_t ws_size,
                              hipStream_t stream) {
  const float* seq  = (const float*)d_in[0];
  const float* Win  = (const float*)d_in[1];
  const float* Wout = (const float*)d_in[2];
  const float* WB   = (const float*)d_in[3];
  const float* WC   = (const float*)d_in[4];
  const float* WD1  = (const float*)d_in[5];
  const float* WD2  = (const float*)d_in[6];
  const float* cw   = (const float*)d_in[7];
  const float* cb   = (const float*)d_in[8];
  const float* A    = (const float*)d_in[9];
  const float* Dv   = (const float*)d_in[10];
  float* out = (float*)d_out;

  float* ws   = (float*)d_ws;
  float* ab   = ws;                   // 2048*2048      = 4194304
  float* x    = ab  + 4194304;        // 2048*1024      = 2097152
  float* dlt  = x   + 2097152;        // 2048*1024      = 2097152
  float* Bm   = dlt + 2097152;        // 2048*16        = 32768
  float* Cm   = Bm  + 32768;          // 32768
  float* t1   = Cm  + 32768;          // 2048*64        = 131072
  float* hc   = t1  + 131072;         // 2*16*1024*16   = 524288
  float* ap   = hc  + 524288;         // 524288
  float* hin  = ap  + 524288;         // 524288
  float* sout = hin + 524288;         // 2097152
  // total ~49 MB of workspace

  gemm_nt<float, float, float><<<dim3((2 * DM) / 64, NROW / 64), dim3(16, 16), 0, stream>>>(
      seq, Win, ab, NROW, 2 * DM, DIN);
  conv_silu_k<<<NROW * DM / 256, 256, 0, stream>>>(ab, cw, cb, x);
  proj96_k<<<NROW, 128, 0, stream>>>(x, WB, WC, WD1, Bm, Cm, t1);
  delta_k<<<dim3(NROW, DM / 256), 256, 0, stream>>>(t1, WD2, Dv, dlt);
  scan1_k<<<B_ * NC * DM / 256, 256, 0, stream>>>(x, dlt, Bm, A, hc, ap);
  scomb_k<<<B_ * DM * DS / 256, 256, 0, stream>>>(hc, ap, hin);
  scan2_k<<<B_ * NC * DM / 256, 256, 0, stream>>>(x, dlt, Bm, Cm, hin, ab, A, Dv, sout);
  gemm_nt<float, float, float><<<dim3(DIN / 64, NROW / 64), dim3(16, 16), 0, stream>>>(
      sout, Wout, out, NROW, DIN, DM);
}

// Round 3
// 263.552 us; speedup vs baseline: 1.9432x; 1.9432x over previous
//
#include <hip/hip_runtime.h>
#include <hip/hip_bf16.h>

using bf16 = __hip_bfloat16;
typedef short short8 __attribute__((ext_vector_type(8)));
typedef float float4v __attribute__((ext_vector_type(4)));

#define B_   2
#define L_   1024
#define DIN  512
#define DM   1024
#define DS   16
#define DD   64
#define KER_ 4
#define NROW (B_*L_)     // 2048
#define LC   32          // scan chunk length
#define NC   (L_/LC)     // 32 chunks

__device__ __forceinline__ float silu_f(float v){ return v / (1.f + expf(-v)); }

// f32 -> bf16 bits, round-to-nearest-even
__device__ __forceinline__ short f2bf(float f) {
  union { float f; unsigned u; } v; v.f = f;
  return (short)((v.u + 0x7FFF + ((v.u >> 16) & 1)) >> 16);
}

// ---------------------------------------------------------------------------
// MFMA NT GEMM: C[M,N] = A[M,K] * B[N,K]^T. A,B f32 (converted to bf16 in
// staging), fp32 accumulate. 256 threads = 4 waves arranged MW x NW; each
// wave computes (MT*16) x (NT*16). BK=32 (one 16x16x32 MFMA per tile pair).
// LDS rows padded to 40 bf16 (80 B) -> worst 2-way bank aliasing (free).
// EP: 0 = plain f32 store; 1 = softplus(v + Dv[col]) (delta epilogue).
// ---------------------------------------------------------------------------
template<int MW, int NW, int MT, int NT, int EP>
__global__ __launch_bounds__(256)
void mfma_nt(const float* __restrict__ A, const float* __restrict__ B,
             float* __restrict__ C, const float* __restrict__ Dv,
             int M, int N, int K, int lda, int ldb, int ldc) {
  constexpr int BM = MW * MT * 16;
  constexpr int BN = NW * NT * 16;
  __shared__ short As[BM * 40];
  __shared__ short Bs[BN * 40];
  const int m0 = blockIdx.y * BM;
  const int n0 = blockIdx.x * BN;
  const int tid  = threadIdx.x;
  const int lane = tid & 63;
  const int wave = tid >> 6;
  const int wm   = wave % MW;
  const int wn   = wave / MW;
  const int r16  = lane & 15;
  const int quad = lane >> 4;

  float4v acc[MT][NT];
#pragma unroll
  for (int i = 0; i < MT; i++)
#pragma unroll
    for (int j = 0; j < NT; j++) acc[i][j] = (float4v){0.f, 0.f, 0.f, 0.f};

  for (int k0 = 0; k0 < K; k0 += 32) {
    // ---- stage A tile (BM x 32) : units of 8 elements -------------------
#pragma unroll 2
    for (int u = tid; u < BM * 4; u += 256) {
      int row = u >> 2, q = u & 3;
      const float4* p = (const float4*)(A + (size_t)(m0 + row) * lda + k0 + q * 8);
      float4 x0 = p[0], x1 = p[1];
      short8 s = { f2bf(x0.x), f2bf(x0.y), f2bf(x0.z), f2bf(x0.w),
                   f2bf(x1.x), f2bf(x1.y), f2bf(x1.z), f2bf(x1.w) };
      *(short8*)&As[row * 40 + q * 8] = s;
    }
    // ---- stage B tile (BN x 32) ----------------------------------------
#pragma unroll 2
    for (int u = tid; u < BN * 4; u += 256) {
      int row = u >> 2, q = u & 3;
      const float4* p = (const float4*)(B + (size_t)(n0 + row) * ldb + k0 + q * 8);
      float4 x0 = p[0], x1 = p[1];
      short8 s = { f2bf(x0.x), f2bf(x0.y), f2bf(x0.z), f2bf(x0.w),
                   f2bf(x1.x), f2bf(x1.y), f2bf(x1.z), f2bf(x1.w) };
      *(short8*)&Bs[row * 40 + q * 8] = s;
    }
    __syncthreads();
    // ---- MFMA ----------------------------------------------------------
    short8 afr[MT], bfr[NT];
#pragma unroll
    for (int mi = 0; mi < MT; mi++)
      afr[mi] = *(const short8*)&As[(wm * MT * 16 + mi * 16 + r16) * 40 + quad * 8];
#pragma unroll
    for (int ni = 0; ni < NT; ni++)
      bfr[ni] = *(const short8*)&Bs[(wn * NT * 16 + ni * 16 + r16) * 40 + quad * 8];
#pragma unroll
    for (int mi = 0; mi < MT; mi++)
#pragma unroll
      for (int ni = 0; ni < NT; ni++)
        acc[mi][ni] = __builtin_amdgcn_mfma_f32_16x16x32_bf16(
            afr[mi], bfr[ni], acc[mi][ni], 0, 0, 0);
    __syncthreads();
  }

  // ---- epilogue: C/D layout col=lane&15, row=quad*4+r ------------------
#pragma unroll
  for (int mi = 0; mi < MT; mi++)
#pragma unroll
    for (int ni = 0; ni < NT; ni++) {
      int gn = n0 + wn * NT * 16 + ni * 16 + r16;
#pragma unroll
      for (int r = 0; r < 4; r++) {
        int gm = m0 + wm * MT * 16 + mi * 16 + quad * 4 + r;
        float v = acc[mi][ni][r];
        if (EP == 1) {
          v += Dv[gn];
          v = fmaxf(v, 0.f) + log1pf(expf(-fabsf(v)));   // stable softplus
        }
        C[(size_t)gm * ldc + gn] = v;
      }
    }
}

// ---------------------------------------------------------------------------
// Gather W_B(16 rows) | W_C(16) | W_D1(64) -> Wcat[96][1024]
// ---------------------------------------------------------------------------
__global__ __launch_bounds__(256)
void wcat_k(const float* __restrict__ WB, const float* __restrict__ WC,
            const float* __restrict__ WD1, float* __restrict__ Wcat) {
  int i = blockIdx.x * 256 + threadIdx.x;   // < 96*1024
  float v;
  if (i < 16 * DM)           v = WB[i];
  else if (i < 32 * DM)      v = WC[i - 16 * DM];
  else                       v = WD1[i - 32 * DM];
  Wcat[i] = v;
}

// ---------------------------------------------------------------------------
// Depthwise causal conv (KER=4) + bias + silu on first half of ab -> x
// ---------------------------------------------------------------------------
__global__ __launch_bounds__(256)
void conv_silu_k(const float* __restrict__ ab, const float* __restrict__ cw,
                 const float* __restrict__ cb, float* __restrict__ x) {
  int idx = blockIdx.x * 256 + threadIdx.x;   // n*DM + d
  int d  = idx & (DM - 1);
  int n  = idx >> 10;
  int l  = n & (L_ - 1);
  int bb = n >> 10;
  float acc = cb[d];
#pragma unroll
  for (int k = 0; k < KER_; k++) {
    int ll = l - (KER_ - 1) + k;
    if (ll >= 0) acc += ab[(size_t)(bb * L_ + ll) * (2 * DM) + d] * cw[d * KER_ + k];
  }
  x[idx] = silu_f(acc);
}

// ---------------------------------------------------------------------------
// Scan pass 1: per (b, chunk, d) local scan carry (prodA[s], h_end[s]).
// Bm rows live inside pall with stride 96.
// ---------------------------------------------------------------------------
__global__ __launch_bounds__(256)
void scan1_k(const float* __restrict__ x, const float* __restrict__ delta,
             const float* __restrict__ Bm, const float* __restrict__ A,
             float* __restrict__ hc, float* __restrict__ ap) {
  int t  = blockIdx.x * 256 + threadIdx.x;   // ((b*NC + c)*DM + d)
  int d  = t & (DM - 1);
  int bc = t >> 10;
  int c  = bc & (NC - 1);
  int b  = bc >> 5;
  float e[DS], h[DS], p[DS];
#pragma unroll
  for (int s = 0; s < DS; s++) { e[s] = expf(-A[d * DS + s]); h[s] = 0.f; p[s] = 1.f; }
  int nbase = b * L_ + c * LC;
  for (int i = 0; i < LC; i++) {
    int n = nbase + i;
    float dl = delta[(size_t)n * DM + d];
    float xv = x[(size_t)n * DM + d];
    float dx = dl * xv;
#pragma unroll
    for (int s = 0; s < DS; s++) {
      float a_ = e[s] * dl;
      h[s] = a_ * h[s] + Bm[n * 96 + s] * dx;
      p[s] *= a_;
    }
  }
#pragma unroll
  for (int s = 0; s < DS; s++) { hc[(size_t)t * DS + s] = h[s]; ap[(size_t)t * DS + s] = p[s]; }
}

// ---------------------------------------------------------------------------
// Combine chunk carries sequentially over NC chunks -> initial h per chunk
// ---------------------------------------------------------------------------
__global__ __launch_bounds__(256)
void scomb_k(const float* __restrict__ hc, const float* __restrict__ ap,
             float* __restrict__ hinit) {
  int t  = blockIdx.x * 256 + threadIdx.x;   // (b*DM + d)*DS + s
  int s  = t & (DS - 1);
  int bd = t >> 4;
  int d  = bd & (DM - 1);
  int b  = bd >> 10;
  float H = 0.f;
  for (int c = 0; c < NC; c++) {
    size_t idx = ((size_t)(b * NC + c) * DM + d) * DS + s;
    hinit[idx] = H;
    H = ap[idx] * H + hc[idx];
  }
}

// ---------------------------------------------------------------------------
// Scan pass 2: replay chunk from hinit; y = sum_s h*Cm + D*x; * silu(gate).
// sout may alias x (read of x[n,d] precedes write of sout[n,d] per i).
// ---------------------------------------------------------------------------
__global__ __launch_bounds__(256)
void scan2_k(const float* __restrict__ x, const float* __restrict__ delta,
             const float* __restrict__ Bm, const float* __restrict__ Cm,
             const float* __restrict__ hinit, const float* __restrict__ ab,
             const float* __restrict__ A, const float* __restrict__ Dv,
             float* __restrict__ sout) {
  int t  = blockIdx.x * 256 + threadIdx.x;
  int d  = t & (DM - 1);
  int bc = t >> 10;
  int c  = bc & (NC - 1);
  int b  = bc >> 5;
  float e[DS], h[DS];
#pragma unroll
  for (int s = 0; s < DS; s++) { e[s] = expf(-A[d * DS + s]); h[s] = hinit[(size_t)t * DS + s]; }
  float Dd = Dv[d];
  int nbase = b * L_ + c * LC;
  for (int i = 0; i < LC; i++) {
    int n = nbase + i;
    float dl = delta[(size_t)n * DM + d];
    float xv = x[(size_t)n * DM + d];
    float dx = dl * xv;
    float y = 0.f;
#pragma unroll
    for (int s = 0; s < DS; s++) {
      h[s] = e[s] * dl * h[s] + Bm[n * 96 + s] * dx;
      y += h[s] * Cm[n * 96 + s];
    }
    y += Dd * xv;
    float g = ab[(size_t)n * (2 * DM) + DM + d];
    sout[(size_t)n * DM + d] = y * silu_f(g);
  }
}

// ---------------------------------------------------------------------------
extern "C" void kernel_launch(void* const* d_in, const int* in_sizes, int n_in,
                              void* d_out, int out_size, void* d_ws, size_t ws_size,
                              hipStream_t stream) {
  const float* seq  = (const float*)d_in[0];
  const float* Win  = (const float*)d_in[1];
  const float* Wout = (const float*)d_in[2];
  const float* WB   = (const float*)d_in[3];
  const float* WC   = (const float*)d_in[4];
  const float* WD1  = (const float*)d_in[5];
  const float* WD2  = (const float*)d_in[6];
  const float* cw   = (const float*)d_in[7];
  const float* cb   = (const float*)d_in[8];
  const float* A    = (const float*)d_in[9];
  const float* Dv   = (const float*)d_in[10];
  float* out = (float*)d_out;

  float* ws   = (float*)d_ws;
  float* ab   = ws;                   // 2048*2048      = 4194304
  float* x    = ab   + 4194304;       // 2048*1024      = 2097152  (scan2 reuses as sout)
  float* dlt  = x    + 2097152;       // 2048*1024      = 2097152
  float* pall = dlt  + 2097152;       // 2048*96        = 196608   (Bm|Cm|t1)
  float* Wcat = pall + 196608;        // 96*1024        = 98304
  float* hc   = Wcat + 98304;         // 2*32*1024*16   = 1048576
  float* ap   = hc   + 1048576;       // 1048576
  float* hin  = ap   + 1048576;       // 1048576
  // total 11.83M floats = 47.3 MB (Round-2's 49 MB worked)
  float* t1   = pall + 32;            // t1 rows start at col 32 (lda=96)
  float* sout = x;                    // alias

  wcat_k<<<96 * DM / 256, 256, 0, stream>>>(WB, WC, WD1, Wcat);
  // GEMM1: ab[2048,2048] = seq[2048,512] . Win[2048,512]^T   (BM=128,BN=64)
  mfma_nt<2, 2, 4, 2, 0><<<dim3((2 * DM) / 64, NROW / 128), 256, 0, stream>>>(
      seq, Win, ab, nullptr, NROW, 2 * DM, DIN, DIN, DIN, 2 * DM);
  conv_silu_k<<<NROW * DM / 256, 256, 0, stream>>>(ab, cw, cb, x);
  // proj: pall[2048,96] = x[2048,1024] . Wcat[96,1024]^T     (BM=64,BN=96)
  mfma_nt<4, 1, 1, 6, 0><<<dim3(1, NROW / 64), 256, 0, stream>>>(
      x, Wcat, pall, nullptr, NROW, 96, DM, DM, DM, 96);
  // delta: dlt[2048,1024] = softplus(t1[2048,64] . WD2[1024,64]^T + Dv)
  mfma_nt<2, 2, 4, 2, 1><<<dim3(DM / 64, NROW / 128), 256, 0, stream>>>(
      t1, WD2, dlt, Dv, NROW, DM, DD, 96, DD, DM);
  scan1_k<<<B_ * NC * DM / 256, 256, 0, stream>>>(x, dlt, pall, A, hc, ap);
  scomb_k<<<B_ * DM * DS / 256, 256, 0, stream>>>(hc, ap, hin);
  scan2_k<<<B_ * NC * DM / 256, 256, 0, stream>>>(x, dlt, pall, pall + 16, hin, ab, A, Dv, sout);
  // GEMM2: out[2048,512] = sout[2048,1024] . Wout[512,1024]^T (BM=64,BN=64)
  mfma_nt<2, 2, 2, 2, 0><<<dim3(DIN / 64, NROW / 64), 256, 0, stream>>>(
      sout, Wout, out, nullptr, NROW, DIN, DM, DM, DM, DIN);
}

// Round 4
// 214.207 us; speedup vs baseline: 2.3909x; 1.2304x over previous
//
#include <hip/hip_runtime.h>
#include <hip/hip_bf16.h>

using bf16 = __hip_bfloat16;
typedef short short8 __attribute__((ext_vector_type(8)));
typedef float float4v __attribute__((ext_vector_type(4)));

#define B_   2
#define L_   1024
#define DIN  512
#define DM   1024
#define DS   16
#define DD   64
#define KER_ 4
#define NROW (B_*L_)     // 2048
#define LC   32          // scan chunk length
#define NC   (L_/LC)     // 32 chunks

__device__ __forceinline__ float silu_f(float v){ return v / (1.f + expf(-v)); }

// f32 -> bf16 bits, round-to-nearest-even
__device__ __forceinline__ short f2bf(float f) {
  union { float f; unsigned u; } v; v.f = f;
  return (short)((v.u + 0x7FFF + ((v.u >> 16) & 1)) >> 16);
}

// ---------------------------------------------------------------------------
// MFMA NT GEMM: C[M,N] = A[M,K] * B[N,K]^T, f32 in (bf16 convert in staging),
// fp32 accumulate. 256 thr = 4 waves (MW x NW), wave tile (MT*16)x(NT*16).
// BK=32. Register-prefetch pipeline: next K-tile's global loads issued right
// after the first barrier so they overlap the MFMA block (exposed-latency fix
// for low-occupancy grids). KS>1 = split-K: block kb covers K/KS, writes
// partials at C + kb*M*ldc (reduced by red_k). EP1: softplus(v+Dv[col]).
// ---------------------------------------------------------------------------
template<int MW, int NW, int MT, int NT, int EP, int KS>
__global__ __launch_bounds__(256)
void mfma_nt(const float* __restrict__ A, const float* __restrict__ B,
             float* __restrict__ C, const float* __restrict__ Dv,
             int M, int N, int K, int lda, int ldb, int ldc) {
  constexpr int BM = MW * MT * 16;
  constexpr int BN = NW * NT * 16;
  constexpr int TU = (BM + BN) * 4;        // 8-elem staging units per K-step
  constexpr int NU = (TU + 255) / 256;     // units per thread
  __shared__ short As[BM * 40];
  __shared__ short Bs[BN * 40];
  const int m0 = blockIdx.y * BM;
  const int n0 = blockIdx.x * BN;
  const int tid  = threadIdx.x;
  const int lane = tid & 63;
  const int wave = tid >> 6;
  const int wm   = wave % MW;
  const int wn   = wave / MW;
  const int r16  = lane & 15;
  const int quad = lane >> 4;
  const int kb   = (KS > 1) ? blockIdx.z : 0;
  const int kper = K / KS;
  const int kbeg = kb * kper;
  const int kend = kbeg + kper;

  float4v acc[MT][NT];
#pragma unroll
  for (int i = 0; i < MT; i++)
#pragma unroll
    for (int j = 0; j < NT; j++) acc[i][j] = (float4v){0.f, 0.f, 0.f, 0.f};

  float4 pf0[NU], pf1[NU];
  auto ldu = [&](int j, int k0) {
    int u = tid + j * 256;
    if (u < TU) {
      const float4* p;
      if (u < BM * 4) {
        int row = u >> 2, q = u & 3;
        p = (const float4*)(A + (size_t)(m0 + row) * lda + k0 + q * 8);
      } else {
        int v = u - BM * 4; int row = v >> 2, q = v & 3;
        p = (const float4*)(B + (size_t)(n0 + row) * ldb + k0 + q * 8);
      }
      pf0[j] = p[0]; pf1[j] = p[1];
    }
  };
  auto stu = [&](int j) {
    int u = tid + j * 256;
    if (u < TU) {
      short8 s = { f2bf(pf0[j].x), f2bf(pf0[j].y), f2bf(pf0[j].z), f2bf(pf0[j].w),
                   f2bf(pf1[j].x), f2bf(pf1[j].y), f2bf(pf1[j].z), f2bf(pf1[j].w) };
      if (u < BM * 4) {
        int row = u >> 2, q = u & 3;
        *(short8*)&As[row * 40 + q * 8] = s;
      } else {
        int v = u - BM * 4; int row = v >> 2, q = v & 3;
        *(short8*)&Bs[row * 40 + q * 8] = s;
      }
    }
  };

#pragma unroll
  for (int j = 0; j < NU; j++) ldu(j, kbeg);

  for (int k0 = kbeg; k0 < kend; k0 += 32) {
#pragma unroll
    for (int j = 0; j < NU; j++) stu(j);
    __syncthreads();
    if (k0 + 32 < kend) {
#pragma unroll
      for (int j = 0; j < NU; j++) ldu(j, k0 + 32);   // overlaps MFMAs below
    }
    short8 afr[MT], bfr[NT];
#pragma unroll
    for (int mi = 0; mi < MT; mi++)
      afr[mi] = *(const short8*)&As[(wm * MT * 16 + mi * 16 + r16) * 40 + quad * 8];
#pragma unroll
    for (int ni = 0; ni < NT; ni++)
      bfr[ni] = *(const short8*)&Bs[(wn * NT * 16 + ni * 16 + r16) * 40 + quad * 8];
#pragma unroll
    for (int mi = 0; mi < MT; mi++)
#pragma unroll
      for (int ni = 0; ni < NT; ni++)
        acc[mi][ni] = __builtin_amdgcn_mfma_f32_16x16x32_bf16(
            afr[mi], bfr[ni], acc[mi][ni], 0, 0, 0);
    __syncthreads();
  }

  // epilogue: C/D layout col=lane&15, row=quad*4+r
  float* Cp = C + (size_t)kb * M * ldc;
#pragma unroll
  for (int mi = 0; mi < MT; mi++)
#pragma unroll
    for (int ni = 0; ni < NT; ni++) {
      int gn = n0 + wn * NT * 16 + ni * 16 + r16;
#pragma unroll
      for (int r = 0; r < 4; r++) {
        int gm = m0 + wm * MT * 16 + mi * 16 + quad * 4 + r;
        float v = acc[mi][ni][r];
        if (EP == 1) {
          v += Dv[gn];
          v = fmaxf(v, 0.f) + log1pf(expf(-fabsf(v)));   // stable softplus
        }
        Cp[(size_t)gm * ldc + gn] = v;
      }
    }
}

// ---------------------------------------------------------------------------
// Split-K reduce: dst[i] = sum_j part[j*nelem + i]
// ---------------------------------------------------------------------------
template<int KS>
__global__ __launch_bounds__(256)
void red_k(const float* __restrict__ part, float* __restrict__ dst, int nelem) {
  int i = blockIdx.x * 256 + threadIdx.x;
  float s = 0.f;
#pragma unroll
  for (int j = 0; j < KS; j++) s += part[(size_t)j * nelem + i];
  dst[i] = s;
}

// ---------------------------------------------------------------------------
// Gather W_B(16 rows) | W_C(16) | W_D1(64) -> Wcat[96][1024]
// ---------------------------------------------------------------------------
__global__ __launch_bounds__(256)
void wcat_k(const float* __restrict__ WB, const float* __restrict__ WC,
            const float* __restrict__ WD1, float* __restrict__ Wcat) {
  int i = blockIdx.x * 256 + threadIdx.x;   // < 96*1024
  float v;
  if (i < 16 * DM)           v = WB[i];
  else if (i < 32 * DM)      v = WC[i - 16 * DM];
  else                       v = WD1[i - 32 * DM];
  Wcat[i] = v;
}

// ---------------------------------------------------------------------------
// Depthwise causal conv (KER=4) + bias + silu on first half of ab -> x
// ---------------------------------------------------------------------------
__global__ __launch_bounds__(256)
void conv_silu_k(const float* __restrict__ ab, const float* __restrict__ cw,
                 const float* __restrict__ cb, float* __restrict__ x) {
  int idx = blockIdx.x * 256 + threadIdx.x;   // n*DM + d
  int d  = idx & (DM - 1);
  int n  = idx >> 10;
  int l  = n & (L_ - 1);
  int bb = n >> 10;
  float acc = cb[d];
#pragma unroll
  for (int k = 0; k < KER_; k++) {
    int ll = l - (KER_ - 1) + k;
    if (ll >= 0) acc += ab[(size_t)(bb * L_ + ll) * (2 * DM) + d] * cw[d * KER_ + k];
  }
  x[idx] = silu_f(acc);
}

// ---------------------------------------------------------------------------
// Scan pass 1: per (b, chunk, d) local carry (prodA[s], h_end[s]).
// Bm rows live inside pall with stride 96.
// ---------------------------------------------------------------------------
__global__ __launch_bounds__(256)
void scan1_k(const float* __restrict__ x, const float* __restrict__ delta,
             const float* __restrict__ Bm, const float* __restrict__ A,
             float* __restrict__ hc, float* __restrict__ ap) {
  int t  = blockIdx.x * 256 + threadIdx.x;   // ((b*NC + c)*DM + d)
  int d  = t & (DM - 1);
  int bc = t >> 10;
  int c  = bc & (NC - 1);
  int b  = bc >> 5;
  float e[DS], h[DS], p[DS];
#pragma unroll
  for (int s = 0; s < DS; s++) { e[s] = expf(-A[d * DS + s]); h[s] = 0.f; p[s] = 1.f; }
  int nbase = b * L_ + c * LC;
  for (int i = 0; i < LC; i++) {
    int n = nbase + i;
    float dl = delta[(size_t)n * DM + d];
    float xv = x[(size_t)n * DM + d];
    float dx = dl * xv;
#pragma unroll
    for (int s = 0; s < DS; s++) {
      float a_ = e[s] * dl;
      h[s] = a_ * h[s] + Bm[n * 96 + s] * dx;
      p[s] *= a_;
    }
  }
#pragma unroll
  for (int s = 0; s < DS; s++) { hc[(size_t)t * DS + s] = h[s]; ap[(size_t)t * DS + s] = p[s]; }
}

// ---------------------------------------------------------------------------
// Combine chunk carries sequentially over NC chunks -> initial h per chunk
// ---------------------------------------------------------------------------
__global__ __launch_bounds__(256)
void scomb_k(const float* __restrict__ hc, const float* __restrict__ ap,
             float* __restrict__ hinit) {
  int t  = blockIdx.x * 256 + threadIdx.x;   // (b*DM + d)*DS + s
  int s  = t & (DS - 1);
  int bd = t >> 4;
  int d  = bd & (DM - 1);
  int b  = bd >> 10;
  float H = 0.f;
  for (int c = 0; c < NC; c++) {
    size_t idx = ((size_t)(b * NC + c) * DM + d) * DS + s;
    hinit[idx] = H;
    H = ap[idx] * H + hc[idx];
  }
}

// ---------------------------------------------------------------------------
// Scan pass 2: replay chunk from hinit; y = sum_s h*Cm + D*x; * silu(gate).
// sout aliases x (read of x[n,d] precedes write of sout[n,d] per i).
// ---------------------------------------------------------------------------
__global__ __launch_bounds__(256)
void scan2_k(const float* __restrict__ x, const float* __restrict__ delta,
             const float* __restrict__ Bm, const float* __restrict__ Cm,
             const float* __restrict__ hinit, const float* __restrict__ ab,
             const float* __restrict__ A, const float* __restrict__ Dv,
             float* __restrict__ sout) {
  int t  = blockIdx.x * 256 + threadIdx.x;
  int d  = t & (DM - 1);
  int bc = t >> 10;
  int c  = bc & (NC - 1);
  int b  = bc >> 5;
  float e[DS], h[DS];
#pragma unroll
  for (int s = 0; s < DS; s++) { e[s] = expf(-A[d * DS + s]); h[s] = hinit[(size_t)t * DS + s]; }
  float Dd = Dv[d];
  int nbase = b * L_ + c * LC;
  for (int i = 0; i < LC; i++) {
    int n = nbase + i;
    float dl = delta[(size_t)n * DM + d];
    float xv = x[(size_t)n * DM + d];
    float dx = dl * xv;
    float y = 0.f;
#pragma unroll
    for (int s = 0; s < DS; s++) {
      h[s] = e[s] * dl * h[s] + Bm[n * 96 + s] * dx;
      y += h[s] * Cm[n * 96 + s];
    }
    y += Dd * xv;
    float g = ab[(size_t)n * (2 * DM) + DM + d];
    sout[(size_t)n * DM + d] = y * silu_f(g);
  }
}

// ---------------------------------------------------------------------------
extern "C" void kernel_launch(void* const* d_in, const int* in_sizes, int n_in,
                              void* d_out, int out_size, void* d_ws, size_t ws_size,
                              hipStream_t stream) {
  const float* seq  = (const float*)d_in[0];
  const float* Win  = (const float*)d_in[1];
  const float* Wout = (const float*)d_in[2];
  const float* WB   = (const float*)d_in[3];
  const float* WC   = (const float*)d_in[4];
  const float* WD1  = (const float*)d_in[5];
  const float* WD2  = (const float*)d_in[6];
  const float* cw   = (const float*)d_in[7];
  const float* cb   = (const float*)d_in[8];
  const float* A    = (const float*)d_in[9];
  const float* Dv   = (const float*)d_in[10];
  float* out = (float*)d_out;

  float* ws   = (float*)d_ws;
  float* ab   = ws;                   // 2048*2048      = 4194304
  float* x    = ab   + 4194304;       // 2048*1024      = 2097152  (scan2 reuses as sout)
  float* dlt  = x    + 2097152;       // 2048*1024      = 2097152
  float* pall = dlt  + 2097152;       // 2048*96        = 196608   (Bm|Cm|t1)
  float* Wcat = pall + 196608;        // 96*1024        = 98304
  float* hc   = Wcat + 98304;         // 2*32*1024*16   = 1048576
  float* ap   = hc   + 1048576;       // 1048576
  float* hin  = ap   + 1048576;       // 1048576
  // total 11.83M floats = 47.3 MB (proven budget)
  float* t1    = pall + 32;           // t1 rows start at col 32 (lda=96)
  float* sout  = x;                   // alias
  float* ppart = dlt;                 // proj split-K partials (8*196608=1572864 <= dlt) — dead before delta writes dlt
  float* gpart = ab;                  // GEMM2 split-K partials (2*1048576 <= ab) — ab dead after scan2

  wcat_k<<<96 * DM / 256, 256, 0, stream>>>(WB, WC, WD1, Wcat);
  // GEMM1: ab[2048,2048] = seq . Win^T   (BM=128,BN=64, 512 blocks)
  mfma_nt<2, 2, 4, 2, 0, 1><<<dim3((2 * DM) / 64, NROW / 128, 1), 256, 0, stream>>>(
      seq, Win, ab, nullptr, NROW, 2 * DM, DIN, DIN, DIN, 2 * DM);
  conv_silu_k<<<NROW * DM / 256, 256, 0, stream>>>(ab, cw, cb, x);
  // proj: pall[2048,96] = x . Wcat^T, split-K x8 (BM=64,BN=96, 256 blocks)
  mfma_nt<4, 1, 1, 6, 0, 8><<<dim3(1, NROW / 64, 8), 256, 0, stream>>>(
      x, Wcat, ppart, nullptr, NROW, 96, DM, DM, DM, 96);
  red_k<8><<<NROW * 96 / 256, 256, 0, stream>>>(ppart, pall, NROW * 96);
  // delta: dlt = softplus(t1 . WD2^T + Dv)   (BM=64,BN=64, 512 blocks)
  mfma_nt<2, 2, 2, 2, 1, 1><<<dim3(DM / 64, NROW / 64, 1), 256, 0, stream>>>(
      t1, WD2, dlt, Dv, NROW, DM, DD, 96, DD, DM);
  scan1_k<<<B_ * NC * DM / 256, 256, 0, stream>>>(x, dlt, pall, A, hc, ap);
  scomb_k<<<B_ * DM * DS / 256, 256, 0, stream>>>(hc, ap, hin);
  scan2_k<<<B_ * NC * DM / 256, 256, 0, stream>>>(x, dlt, pall, pall + 16, hin, ab, A, Dv, sout);
  // GEMM2: out = sout . Wout^T, split-K x2 (BM=64,BN=64, 512 blocks)
  mfma_nt<2, 2, 2, 2, 0, 2><<<dim3(DIN / 64, NROW / 64, 2), 256, 0, stream>>>(
      sout, Wout, gpart, nullptr, NROW, DIN, DM, DM, DM, DIN);
  red_k<2><<<NROW * DIN / 256, 256, 0, stream>>>(gpart, out, NROW * DIN);
}

// Round 5
// 185.129 us; speedup vs baseline: 2.7664x; 1.1571x over previous
//
#include <hip/hip_runtime.h>
#include <hip/hip_bf16.h>

using bf16 = __hip_bfloat16;
typedef short short8 __attribute__((ext_vector_type(8)));
typedef float float4v __attribute__((ext_vector_type(4)));

#define B_   2
#define L_   1024
#define DIN  512
#define DM   1024
#define DS   16
#define DD   64
#define KER_ 4
#define NROW (B_*L_)     // 2048

// fused scan geometry: block = (b, 8 d-lanes); 32 chunks x 32 steps = L
#define SD   8
#define SC   32
#define SLC  32
#define SDP  9           // padded dd stride in LDS (bank spread)

__device__ __forceinline__ float silu_f(float v){ return v / (1.f + expf(-v)); }

// f32 -> bf16 bits, round-to-nearest-even
__device__ __forceinline__ short f2bf(float f) {
  union { float f; unsigned u; } v; v.f = f;
  return (short)((v.u + 0x7FFF + ((v.u >> 16) & 1)) >> 16);
}

// ---------------------------------------------------------------------------
// MFMA NT GEMM: C[M,N] = A[M,K] * B[N,K]^T, f32 in (bf16 convert in staging),
// fp32 accumulate. 256 thr = 4 waves (MW x NW), wave tile (MT*16)x(NT*16).
// BK=32, register-prefetch pipeline (next tile's loads overlap MFMA block).
// KS>1: split-K, partials at C + kb*M*ldc. EP1: softplus(v+Dv[col]).
// B3SRC: B is three stacked row-sources WB(16) | WC(16) | WD1(64) (proj).
// ---------------------------------------------------------------------------
template<int MW, int NW, int MT, int NT, int EP, int KS, int B3SRC>
__global__ __launch_bounds__(256)
void mfma_nt(const float* __restrict__ A, const float* __restrict__ B,
             const float* __restrict__ B2, const float* __restrict__ B3,
             float* __restrict__ C, const float* __restrict__ Dv,
             int M, int N, int K, int lda, int ldb, int ldc) {
  constexpr int BM = MW * MT * 16;
  constexpr int BN = NW * NT * 16;
  constexpr int TU = (BM + BN) * 4;        // 8-elem staging units per K-step
  constexpr int NU = (TU + 255) / 256;     // units per thread
  __shared__ short As[BM * 40];
  __shared__ short Bs[BN * 40];
  const int m0 = blockIdx.y * BM;
  const int n0 = blockIdx.x * BN;
  const int tid  = threadIdx.x;
  const int lane = tid & 63;
  const int wave = tid >> 6;
  const int wm   = wave % MW;
  const int wn   = wave / MW;
  const int r16  = lane & 15;
  const int quad = lane >> 4;
  const int kb   = (KS > 1) ? blockIdx.z : 0;
  const int kper = K / KS;
  const int kbeg = kb * kper;
  const int kend = kbeg + kper;

  float4v acc[MT][NT];
#pragma unroll
  for (int i = 0; i < MT; i++)
#pragma unroll
    for (int j = 0; j < NT; j++) acc[i][j] = (float4v){0.f, 0.f, 0.f, 0.f};

  float4 pf0[NU], pf1[NU];
  auto ldu = [&](int j, int k0) {
    int u = tid + j * 256;
    if (u < TU) {
      const float4* p;
      if (u < BM * 4) {
        int row = u >> 2, q = u & 3;
        p = (const float4*)(A + (size_t)(m0 + row) * lda + k0 + q * 8);
      } else {
        int v = u - BM * 4; int row = v >> 2, q = v & 3;
        if (B3SRC) {
          int r = n0 + row;
          const float* bp = (r < 16) ? (B + (size_t)r * ldb)
                          : (r < 32) ? (B2 + (size_t)(r - 16) * ldb)
                                     : (B3 + (size_t)(r - 32) * ldb);
          p = (const float4*)(bp + k0 + q * 8);
        } else {
          p = (const float4*)(B + (size_t)(n0 + row) * ldb + k0 + q * 8);
        }
      }
      pf0[j] = p[0]; pf1[j] = p[1];
    }
  };
  auto stu = [&](int j) {
    int u = tid + j * 256;
    if (u < TU) {
      short8 s = { f2bf(pf0[j].x), f2bf(pf0[j].y), f2bf(pf0[j].z), f2bf(pf0[j].w),
                   f2bf(pf1[j].x), f2bf(pf1[j].y), f2bf(pf1[j].z), f2bf(pf1[j].w) };
      if (u < BM * 4) {
        int row = u >> 2, q = u & 3;
        *(short8*)&As[row * 40 + q * 8] = s;
      } else {
        int v = u - BM * 4; int row = v >> 2, q = v & 3;
        *(short8*)&Bs[row * 40 + q * 8] = s;
      }
    }
  };

#pragma unroll
  for (int j = 0; j < NU; j++) ldu(j, kbeg);

  for (int k0 = kbeg; k0 < kend; k0 += 32) {
#pragma unroll
    for (int j = 0; j < NU; j++) stu(j);
    __syncthreads();
    if (k0 + 32 < kend) {
#pragma unroll
      for (int j = 0; j < NU; j++) ldu(j, k0 + 32);   // overlaps MFMAs below
    }
    short8 afr[MT], bfr[NT];
#pragma unroll
    for (int mi = 0; mi < MT; mi++)
      afr[mi] = *(const short8*)&As[(wm * MT * 16 + mi * 16 + r16) * 40 + quad * 8];
#pragma unroll
    for (int ni = 0; ni < NT; ni++)
      bfr[ni] = *(const short8*)&Bs[(wn * NT * 16 + ni * 16 + r16) * 40 + quad * 8];
#pragma unroll
    for (int mi = 0; mi < MT; mi++)
#pragma unroll
      for (int ni = 0; ni < NT; ni++)
        acc[mi][ni] = __builtin_amdgcn_mfma_f32_16x16x32_bf16(
            afr[mi], bfr[ni], acc[mi][ni], 0, 0, 0);
    __syncthreads();
  }

  // epilogue: C/D layout col=lane&15, row=quad*4+r
  float* Cp = C + (size_t)kb * M * ldc;
#pragma unroll
  for (int mi = 0; mi < MT; mi++)
#pragma unroll
    for (int ni = 0; ni < NT; ni++) {
      int gn = n0 + wn * NT * 16 + ni * 16 + r16;
#pragma unroll
      for (int r = 0; r < 4; r++) {
        int gm = m0 + wm * MT * 16 + mi * 16 + quad * 4 + r;
        float v = acc[mi][ni][r];
        if (EP == 1) {
          v += Dv[gn];
          v = fmaxf(v, 0.f) + log1pf(expf(-fabsf(v)));   // stable softplus
        }
        Cp[(size_t)gm * ldc + gn] = v;
      }
    }
}

// ---------------------------------------------------------------------------
// Split-K reduce: dst[i] = sum_j part[j*nelem + i]
// ---------------------------------------------------------------------------
template<int KS>
__global__ __launch_bounds__(256)
void red_k(const float* __restrict__ part, float* __restrict__ dst, int nelem) {
  int i = blockIdx.x * 256 + threadIdx.x;
  float s = 0.f;
#pragma unroll
  for (int j = 0; j < KS; j++) s += part[(size_t)j * nelem + i];
  dst[i] = s;
}

// ---------------------------------------------------------------------------
// Depthwise causal conv (KER=4) + bias + silu on first half of ab -> x
// ---------------------------------------------------------------------------
__global__ __launch_bounds__(256)
void conv_silu_k(const float* __restrict__ ab, const float* __restrict__ cw,
                 const float* __restrict__ cb, float* __restrict__ x) {
  int idx = blockIdx.x * 256 + threadIdx.x;   // n*DM + d
  int d  = idx & (DM - 1);
  int n  = idx >> 10;
  int l  = n & (L_ - 1);
  int bb = n >> 10;
  float acc = cb[d];
#pragma unroll
  for (int k = 0; k < KER_; k++) {
    int ll = l - (KER_ - 1) + k;
    if (ll >= 0) acc += ab[(size_t)(bb * L_ + ll) * (2 * DM) + d] * cw[d * KER_ + k];
  }
  x[idx] = silu_f(acc);
}

// ---------------------------------------------------------------------------
// Fused selective scan: one block per (b, 8 d-lanes). All 32 chunks of each
// (b,d) are block-local, so the chunk-carry combine is an LDS scan — no
// global hc/ap/hinit round-trip. Phase A: per-thread local chunk scan ->
// carries. Phase B: 128 threads serially combine 32 chunks. Phase C: replay
// from hinit, y = sum_s h*Cm + D*x, out = y * silu(gate).
// sout may alias x (each (n,d) element is owned by exactly one thread and
// read before written). Arithmetic order identical to the 3-kernel version.
// ---------------------------------------------------------------------------
__global__ __launch_bounds__(256)
void scan_fused_k(const float* __restrict__ x, const float* __restrict__ dlt,
                  const float* __restrict__ pall, const float* __restrict__ A,
                  const float* __restrict__ Dv, const float* __restrict__ ab,
                  float* __restrict__ sout) {
  __shared__ float Pl[SC][DS][SDP];
  __shared__ float Hl[SC][DS][SDP];
  const int blk = blockIdx.x;             // b*(DM/SD) + dblk
  const int b   = blk >> 7;
  const int d0  = (blk & 127) * SD;
  const int dd  = threadIdx.x & (SD - 1);
  const int c   = threadIdx.x >> 3;
  const int d   = d0 + dd;

  float e[DS];
#pragma unroll
  for (int s = 0; s < DS; s++) e[s] = expf(-A[d * DS + s]);
  const int nbase = b * L_ + c * SLC;

  // ---- phase A: local chunk scan -> carries (p, h) ---------------------
  float h[DS], p[DS];
#pragma unroll
  for (int s = 0; s < DS; s++) { h[s] = 0.f; p[s] = 1.f; }
  for (int i = 0; i < SLC; i++) {
    int n = nbase + i;
    float dl = dlt[(size_t)n * DM + d];
    float xv = x[(size_t)n * DM + d];
    float dx = dl * xv;
    const float4* bm4 = (const float4*)(pall + (size_t)n * 96);
    float4 b0 = bm4[0], b1 = bm4[1], b2 = bm4[2], b3 = bm4[3];
    const float* bm = (const float*)&b0;   // b0..b3 contiguous? not guaranteed — use explicit
    float bmv[DS] = { b0.x,b0.y,b0.z,b0.w, b1.x,b1.y,b1.z,b1.w,
                      b2.x,b2.y,b2.z,b2.w, b3.x,b3.y,b3.z,b3.w };
    (void)bm;
#pragma unroll
    for (int s = 0; s < DS; s++) {
      float a_ = e[s] * dl;
      h[s] = a_ * h[s] + bmv[s] * dx;
      p[s] *= a_;
    }
  }
#pragma unroll
  for (int s = 0; s < DS; s++) { Pl[c][s][dd] = p[s]; Hl[c][s][dd] = h[s]; }
  __syncthreads();

  // ---- phase B: combine 32 chunk carries per (s, dd) -------------------
  if (threadIdx.x < DS * SD) {
    int s2  = threadIdx.x >> 3;
    int dd2 = threadIdx.x & (SD - 1);
    float H = 0.f;
    for (int c2 = 0; c2 < SC; c2++) {
      float pp = Pl[c2][s2][dd2];
      float hh = Hl[c2][s2][dd2];
      Pl[c2][s2][dd2] = H;                 // hinit for chunk c2
      H = pp * H + hh;
    }
  }
  __syncthreads();

  // ---- phase C: replay from hinit with fused epilogue ------------------
#pragma unroll
  for (int s = 0; s < DS; s++) h[s] = Pl[c][s][dd];
  float Dd = Dv[d];
  for (int i = 0; i < SLC; i++) {
    int n = nbase + i;
    float dl = dlt[(size_t)n * DM + d];
    float xv = x[(size_t)n * DM + d];
    float dx = dl * xv;
    const float4* bm4 = (const float4*)(pall + (size_t)n * 96);
    float4 b0 = bm4[0], b1 = bm4[1], b2 = bm4[2], b3 = bm4[3];
    float4 c0 = bm4[4], c1 = bm4[5], c2v = bm4[6], c3 = bm4[7];
    float bmv[DS] = { b0.x,b0.y,b0.z,b0.w, b1.x,b1.y,b1.z,b1.w,
                      b2.x,b2.y,b2.z,b2.w, b3.x,b3.y,b3.z,b3.w };
    float cmv[DS] = { c0.x,c0.y,c0.z,c0.w, c1.x,c1.y,c1.z,c1.w,
                      c2v.x,c2v.y,c2v.z,c2v.w, c3.x,c3.y,c3.z,c3.w };
    float y = 0.f;
#pragma unroll
    for (int s = 0; s < DS; s++) {
      h[s] = e[s] * dl * h[s] + bmv[s] * dx;
      y += h[s] * cmv[s];
    }
    y += Dd * xv;
    float g = ab[(size_t)n * (2 * DM) + DM + d];
    sout[(size_t)n * DM + d] = y * silu_f(g);
  }
}

// ---------------------------------------------------------------------------
extern "C" void kernel_launch(void* const* d_in, const int* in_sizes, int n_in,
                              void* d_out, int out_size, void* d_ws, size_t ws_size,
                              hipStream_t stream) {
  const float* seq  = (const float*)d_in[0];
  const float* Win  = (const float*)d_in[1];
  const float* Wout = (const float*)d_in[2];
  const float* WB   = (const float*)d_in[3];
  const float* WC   = (const float*)d_in[4];
  const float* WD1  = (const float*)d_in[5];
  const float* WD2  = (const float*)d_in[6];
  const float* cw   = (const float*)d_in[7];
  const float* cb   = (const float*)d_in[8];
  const float* A    = (const float*)d_in[9];
  const float* Dv   = (const float*)d_in[10];
  float* out = (float*)d_out;

  float* ws   = (float*)d_ws;
  float* ab   = ws;                   // 2048*2048 = 4194304
  float* x    = ab   + 4194304;       // 2048*1024 = 2097152 (scan reuses as sout)
  float* dlt  = x    + 2097152;       // 2097152
  float* pall = dlt  + 2097152;       // 2048*96   = 196608  (Bm|Cm|t1)
  // total 8.68M floats = 34.7 MB
  float* t1    = pall + 32;           // t1 rows start at col 32 (lda=96)
  float* sout  = x;                   // alias
  float* ppart = dlt;                 // proj split-K partials (8*196608 <= 2097152), dead before delta
  float* gpart = ab;                  // GEMM2 split-K partials (2*1048576 <= ab), ab dead after scan

  // GEMM1: ab[2048,2048] = seq . Win^T   (BM=128,BN=64, 512 blocks)
  mfma_nt<2, 2, 4, 2, 0, 1, 0><<<dim3((2 * DM) / 64, NROW / 128, 1), 256, 0, stream>>>(
      seq, Win, nullptr, nullptr, ab, nullptr, NROW, 2 * DM, DIN, DIN, DIN, 2 * DM);
  conv_silu_k<<<NROW * DM / 256, 256, 0, stream>>>(ab, cw, cb, x);
  // proj: ppart = x . [WB|WC|WD1]^T, split-K x8 (BM=64,BN=96, 256 blocks)
  mfma_nt<4, 1, 1, 6, 0, 8, 1><<<dim3(1, NROW / 64, 8), 256, 0, stream>>>(
      x, WB, WC, WD1, ppart, nullptr, NROW, 96, DM, DM, DM, 96);
  red_k<8><<<NROW * 96 / 256, 256, 0, stream>>>(ppart, pall, NROW * 96);
  // delta: dlt = softplus(t1 . WD2^T + Dv)   (BM=64,BN=64, 512 blocks)
  mfma_nt<2, 2, 2, 2, 1, 1, 0><<<dim3(DM / 64, NROW / 64, 1), 256, 0, stream>>>(
      t1, WD2, nullptr, nullptr, dlt, Dv, NROW, DM, DD, 96, DD, DM);
  // fused selective scan (256 blocks)
  scan_fused_k<<<B_ * (DM / SD), 256, 0, stream>>>(x, dlt, pall, A, Dv, ab, sout);
  // GEMM2: out = sout . Wout^T, split-K x2 (BM=64,BN=64, 512 blocks)
  mfma_nt<2, 2, 2, 2, 0, 2, 0><<<dim3(DIN / 64, NROW / 64, 2), 256, 0, stream>>>(
      sout, Wout, nullptr, nullptr, gpart, nullptr, NROW, DIN, DM, DM, DM, DIN);
  red_k<2><<<NROW * DIN / 256, 256, 0, stream>>>(gpart, out, NROW * DIN);
}

// Round 6
// 180.425 us; speedup vs baseline: 2.8385x; 1.0261x over previous
//
#include <hip/hip_runtime.h>
#include <hip/hip_bf16.h>

using bf16 = __hip_bfloat16;
typedef short short8 __attribute__((ext_vector_type(8)));
typedef float float4v __attribute__((ext_vector_type(4)));

#define B_   2
#define L_   1024
#define DIN  512
#define DM   1024
#define DS   16
#define DD   64
#define KER_ 4
#define NROW (B_*L_)     // 2048

// fused scan geometry: block = (b, 8 d-lanes); 32 chunks x 32 steps = L
#define SD   8
#define SC   32
#define SLC  32
#define SDP  9           // padded dd stride in LDS

__device__ __forceinline__ float silu_f(float v){ return v / (1.f + expf(-v)); }

// packed f32x2 -> bf16x2 (v_cvt_pk_bf16_f32 on gfx950), RNE
__device__ __forceinline__ short2 f2bf2(float a, float b) {
  __hip_bfloat162 h = __float22bfloat162_rn(float2{a, b});
  union { __hip_bfloat162 h; short2 s; } u; u.h = h; return u.s;
}

// ---------------------------------------------------------------------------
// MFMA NT GEMM: C[M,N] = A[M,K] * B[N,K]^T, f32 in (packed bf16 convert in
// staging), fp32 accumulate. 256 thr = 4 waves (MW x NW). BK=32, register-
// prefetch pipeline. KS>1: split-K over blockIdx.z.
// EP: 0 plain store, 1 softplus(v+Dv[col]) store, 2 atomicAdd into C.
// B3SRC: B rows from WB(16)|WC(16)|WD1(64).
// CONVA: A[m][k] is computed on the fly as silu(causal_conv(ab)[m][k]) —
//        abp is the raw GEMM1 output (row stride lda), cw/cb conv params.
// ---------------------------------------------------------------------------
template<int MW, int NW, int MT, int NT, int EP, int KS, int B3SRC, int CONVA>
__global__ __launch_bounds__(256)
void mfma_nt(const float* __restrict__ A, const float* __restrict__ B,
             const float* __restrict__ B2, const float* __restrict__ B3,
             float* __restrict__ C, const float* __restrict__ Dv,
             const float* __restrict__ abp, const float* __restrict__ cw,
             const float* __restrict__ cb,
             int M, int N, int K, int lda, int ldb, int ldc) {
  constexpr int BM = MW * MT * 16;
  constexpr int BN = NW * NT * 16;
  constexpr int TU = (BM + BN) * 4;        // 8-elem staging units per K-step
  constexpr int NU = (TU + 255) / 256;
  __shared__ short As[BM * 40];
  __shared__ short Bs[BN * 40];
  const int m0 = blockIdx.y * BM;
  const int n0 = blockIdx.x * BN;
  const int tid  = threadIdx.x;
  const int lane = tid & 63;
  const int wave = tid >> 6;
  const int wm   = wave % MW;
  const int wn   = wave / MW;
  const int r16  = lane & 15;
  const int quad = lane >> 4;
  const int kb   = (KS > 1) ? blockIdx.z : 0;
  const int kper = K / KS;
  const int kbeg = kb * kper;
  const int kend = kbeg + kper;

  float4v acc[MT][NT];
#pragma unroll
  for (int i = 0; i < MT; i++)
#pragma unroll
    for (int j = 0; j < NT; j++) acc[i][j] = (float4v){0.f, 0.f, 0.f, 0.f};

  float4 pf0[NU], pf1[NU];
  auto ldu = [&](int j, int k0) {
    int u = tid + j * 256;
    if (u >= TU) return;
    if (CONVA && u < BM * 4) {
      // A element (n, d) = silu(cb[d] + sum_t ab[l-3+t, d]*cw[d*4+t])
      int row = u >> 2, q = u & 3;
      int n = m0 + row, l = n & (L_ - 1), bq = n >> 10;
      float4 tap0[KER_], tap1[KER_];
#pragma unroll
      for (int t = 0; t < KER_; t++) {
        int ll = l - (KER_ - 1) + t;
        if (ll >= 0) {
          const float4* p = (const float4*)(abp + (size_t)(bq * L_ + ll) * lda + k0 + q * 8);
          tap0[t] = p[0]; tap1[t] = p[1];
        } else {
          tap0[t] = float4{0.f,0.f,0.f,0.f}; tap1[t] = float4{0.f,0.f,0.f,0.f};
        }
      }
      float r[8];
#pragma unroll
      for (int e = 0; e < 8; e++) {
        int d = k0 + q * 8 + e;
        float4 w = *(const float4*)(cw + d * 4);
        float a = cb[d];
#pragma unroll
        for (int t = 0; t < KER_; t++) {
          float te = (e < 4) ? (&tap0[t].x)[e] : (&tap1[t].x)[e - 4];
          a += te * (&w.x)[t];
        }
        r[e] = silu_f(a);
      }
      pf0[j] = float4{r[0], r[1], r[2], r[3]};
      pf1[j] = float4{r[4], r[5], r[6], r[7]};
      return;
    }
    const float4* p;
    if (u < BM * 4) {
      int row = u >> 2, q = u & 3;
      p = (const float4*)(A + (size_t)(m0 + row) * lda + k0 + q * 8);
    } else {
      int v = u - BM * 4; int row = v >> 2, q = v & 3;
      if (B3SRC) {
        int rr = n0 + row;
        const float* bp = (rr < 16) ? (B + (size_t)rr * ldb)
                        : (rr < 32) ? (B2 + (size_t)(rr - 16) * ldb)
                                    : (B3 + (size_t)(rr - 32) * ldb);
        p = (const float4*)(bp + k0 + q * 8);
      } else {
        p = (const float4*)(B + (size_t)(n0 + row) * ldb + k0 + q * 8);
      }
    }
    pf0[j] = p[0]; pf1[j] = p[1];
  };
  auto stu = [&](int j) {
    int u = tid + j * 256;
    if (u >= TU) return;
    short2 s0 = f2bf2(pf0[j].x, pf0[j].y), s1 = f2bf2(pf0[j].z, pf0[j].w);
    short2 s2 = f2bf2(pf1[j].x, pf1[j].y), s3 = f2bf2(pf1[j].z, pf1[j].w);
    short8 s = { s0.x, s0.y, s1.x, s1.y, s2.x, s2.y, s3.x, s3.y };
    if (u < BM * 4) {
      int row = u >> 2, q = u & 3;
      *(short8*)&As[row * 40 + q * 8] = s;
    } else {
      int v = u - BM * 4; int row = v >> 2, q = v & 3;
      *(short8*)&Bs[row * 40 + q * 8] = s;
    }
  };

#pragma unroll
  for (int j = 0; j < NU; j++) ldu(j, kbeg);

  for (int k0 = kbeg; k0 < kend; k0 += 32) {
#pragma unroll
    for (int j = 0; j < NU; j++) stu(j);
    __syncthreads();
    if (k0 + 32 < kend) {
#pragma unroll
      for (int j = 0; j < NU; j++) ldu(j, k0 + 32);   // overlaps MFMAs below
    }
    short8 afr[MT], bfr[NT];
#pragma unroll
    for (int mi = 0; mi < MT; mi++)
      afr[mi] = *(const short8*)&As[(wm * MT * 16 + mi * 16 + r16) * 40 + quad * 8];
#pragma unroll
    for (int ni = 0; ni < NT; ni++)
      bfr[ni] = *(const short8*)&Bs[(wn * NT * 16 + ni * 16 + r16) * 40 + quad * 8];
#pragma unroll
    for (int mi = 0; mi < MT; mi++)
#pragma unroll
      for (int ni = 0; ni < NT; ni++)
        acc[mi][ni] = __builtin_amdgcn_mfma_f32_16x16x32_bf16(
            afr[mi], bfr[ni], acc[mi][ni], 0, 0, 0);
    __syncthreads();
  }

  // epilogue: C/D layout col=lane&15, row=quad*4+r
  float* Cp = C + ((EP == 2) ? (size_t)0 : (size_t)kb * M * ldc);
#pragma unroll
  for (int mi = 0; mi < MT; mi++)
#pragma unroll
    for (int ni = 0; ni < NT; ni++) {
      int gn = n0 + wn * NT * 16 + ni * 16 + r16;
#pragma unroll
      for (int r = 0; r < 4; r++) {
        int gm = m0 + wm * MT * 16 + mi * 16 + quad * 4 + r;
        float v = acc[mi][ni][r];
        if (EP == 1) {
          v += Dv[gn];
          v = fmaxf(v, 0.f) + log1pf(expf(-fabsf(v)));   // stable softplus
          Cp[(size_t)gm * ldc + gn] = v;
        } else if (EP == 2) {
          atomicAdd(&Cp[(size_t)gm * ldc + gn], v);
        } else {
          Cp[(size_t)gm * ldc + gn] = v;
        }
      }
    }
}

// ---------------------------------------------------------------------------
// Fused selective scan. Block = (b, 8 d-lanes); chunk combine is LDS-local.
// x = silu(conv(ab)) is recomputed on the fly with a rolling 3-register
// window (conv is sequential along the scan axis). Phases: A local chunk
// scan -> carries; B serial combine of 32 chunk carries; C replay + fused
// y/gate epilogue.
// ---------------------------------------------------------------------------
__global__ __launch_bounds__(256)
void scan_fused_k(const float* __restrict__ ab, const float* __restrict__ dlt,
                  const float* __restrict__ pall, const float* __restrict__ A,
                  const float* __restrict__ Dv, const float* __restrict__ cw,
                  const float* __restrict__ cb, float* __restrict__ sout) {
  __shared__ float Pl[SC][DS][SDP];
  __shared__ float Hl[SC][DS][SDP];
  const int blk = blockIdx.x;             // b*(DM/SD) + dblk
  const int b   = blk >> 7;
  const int d0  = (blk & 127) * SD;
  const int dd  = threadIdx.x & (SD - 1);
  const int c   = threadIdx.x >> 3;
  const int d   = d0 + dd;

  float e[DS];
#pragma unroll
  for (int s = 0; s < DS; s++) e[s] = expf(-A[d * DS + s]);
  const int   lbase = c * SLC;
  const int   nbase = b * L_ + lbase;
  const float4 w    = *(const float4*)(cw + d * 4);
  const float  cbv  = cb[d];

  auto abA = [&](int l) -> float {        // raw pre-conv activation at (b,l,d)
    return (l >= 0) ? ab[(size_t)(b * L_ + l) * (2 * DM) + d] : 0.f;
  };

  // ---- phase A: local chunk scan -> carries (p, h) ---------------------
  float r0 = abA(lbase - 3), r1 = abA(lbase - 2), r2 = abA(lbase - 1);
  float h[DS], p[DS];
#pragma unroll
  for (int s = 0; s < DS; s++) { h[s] = 0.f; p[s] = 1.f; }
  for (int i = 0; i < SLC; i++) {
    int n = nbase + i;
    float a3 = ab[(size_t)n * (2 * DM) + d];
    float xv = silu_f(cbv + r0 * w.x + r1 * w.y + r2 * w.z + a3 * w.w);
    r0 = r1; r1 = r2; r2 = a3;
    float dl = dlt[(size_t)n * DM + d];
    float dx = dl * xv;
    const float4* bm4 = (const float4*)(pall + (size_t)n * 96);
    float4 b0 = bm4[0], b1 = bm4[1], b2 = bm4[2], b3 = bm4[3];
    float bmv[DS] = { b0.x,b0.y,b0.z,b0.w, b1.x,b1.y,b1.z,b1.w,
                      b2.x,b2.y,b2.z,b2.w, b3.x,b3.y,b3.z,b3.w };
#pragma unroll
    for (int s = 0; s < DS; s++) {
      float a_ = e[s] * dl;
      h[s] = a_ * h[s] + bmv[s] * dx;
      p[s] *= a_;
    }
  }
#pragma unroll
  for (int s = 0; s < DS; s++) { Pl[c][s][dd] = p[s]; Hl[c][s][dd] = h[s]; }
  __syncthreads();

  // ---- phase B: combine 32 chunk carries per (s, dd) -------------------
  if (threadIdx.x < DS * SD) {
    int s2  = threadIdx.x >> 3;
    int dd2 = threadIdx.x & (SD - 1);
    float H = 0.f;
    for (int c2 = 0; c2 < SC; c2++) {
      float pp = Pl[c2][s2][dd2];
      float hh = Hl[c2][s2][dd2];
      Pl[c2][s2][dd2] = H;                 // hinit for chunk c2
      H = pp * H + hh;
    }
  }
  __syncthreads();

  // ---- phase C: replay from hinit with fused epilogue ------------------
#pragma unroll
  for (int s = 0; s < DS; s++) h[s] = Pl[c][s][dd];
  float Dd = Dv[d];
  r0 = abA(lbase - 3); r1 = abA(lbase - 2); r2 = abA(lbase - 1);
  for (int i = 0; i < SLC; i++) {
    int n = nbase + i;
    float a3 = ab[(size_t)n * (2 * DM) + d];
    float xv = silu_f(cbv + r0 * w.x + r1 * w.y + r2 * w.z + a3 * w.w);
    r0 = r1; r1 = r2; r2 = a3;
    float dl = dlt[(size_t)n * DM + d];
    float dx = dl * xv;
    const float4* bm4 = (const float4*)(pall + (size_t)n * 96);
    float4 b0 = bm4[0], b1 = bm4[1], b2 = bm4[2], b3 = bm4[3];
    float4 c0 = bm4[4], c1 = bm4[5], c2v = bm4[6], c3 = bm4[7];
    float bmv[DS] = { b0.x,b0.y,b0.z,b0.w, b1.x,b1.y,b1.z,b1.w,
                      b2.x,b2.y,b2.z,b2.w, b3.x,b3.y,b3.z,b3.w };
    float cmv[DS] = { c0.x,c0.y,c0.z,c0.w, c1.x,c1.y,c1.z,c1.w,
                      c2v.x,c2v.y,c2v.z,c2v.w, c3.x,c3.y,c3.z,c3.w };
    float y = 0.f;
#pragma unroll
    for (int s = 0; s < DS; s++) {
      h[s] = e[s] * dl * h[s] + bmv[s] * dx;
      y += h[s] * cmv[s];
    }
    y += Dd * xv;
    float g = ab[(size_t)n * (2 * DM) + DM + d];
    sout[(size_t)n * DM + d] = y * silu_f(g);
  }
}

// ---------------------------------------------------------------------------
extern "C" void kernel_launch(void* const* d_in, const int* in_sizes, int n_in,
                              void* d_out, int out_size, void* d_ws, size_t ws_size,
                              hipStream_t stream) {
  const float* seq  = (const float*)d_in[0];
  const float* Win  = (const float*)d_in[1];
  const float* Wout = (const float*)d_in[2];
  const float* WB   = (const float*)d_in[3];
  const float* WC   = (const float*)d_in[4];
  const float* WD1  = (const float*)d_in[5];
  const float* WD2  = (const float*)d_in[6];
  const float* cw   = (const float*)d_in[7];
  const float* cb   = (const float*)d_in[8];
  const float* A    = (const float*)d_in[9];
  const float* Dv   = (const float*)d_in[10];
  float* out = (float*)d_out;

  float* ws   = (float*)d_ws;
  float* ab   = ws;                   // 2048*2048 = 4194304
  float* dlt  = ab   + 4194304;       // 2048*1024 = 2097152
  float* pall = dlt  + 2097152;       // 2048*96   = 196608 (Bm|Cm|t1, atomic-accumulated)
  float* sout = pall + 196608;        // 2097152
  // total 8.59M floats = 34.3 MB
  float* t1   = pall + 32;            // t1 rows start at col 32 (lda=96)

  hipMemsetAsync(out, 0, (size_t)NROW * DIN * 4, stream);
  hipMemsetAsync(pall, 0, (size_t)NROW * 96 * 4, stream);
  // GEMM1: ab[2048,2048] = seq . Win^T   (BM=128,BN=64, 512 blocks)
  mfma_nt<2, 2, 4, 2, 0, 1, 0, 0><<<dim3((2 * DM) / 64, NROW / 128, 1), 256, 0, stream>>>(
      seq, Win, nullptr, nullptr, ab, nullptr, nullptr, nullptr, nullptr,
      NROW, 2 * DM, DIN, DIN, DIN, 2 * DM);
  // proj: pall += silu(conv(ab)) . [WB|WC|WD1]^T, split-K x8, atomic epilogue
  mfma_nt<4, 1, 1, 6, 2, 8, 1, 1><<<dim3(1, NROW / 64, 8), 256, 0, stream>>>(
      nullptr, WB, WC, WD1, pall, nullptr, ab, cw, cb,
      NROW, 96, DM, 2 * DM, DM, 96);
  // delta: dlt = softplus(t1 . WD2^T + Dv)   (BM=64,BN=64, 512 blocks)
  mfma_nt<2, 2, 2, 2, 1, 1, 0, 0><<<dim3(DM / 64, NROW / 64, 1), 256, 0, stream>>>(
      t1, WD2, nullptr, nullptr, dlt, Dv, nullptr, nullptr, nullptr,
      NROW, DM, DD, 96, DD, DM);
  // fused selective scan (256 blocks), conv recomputed on the fly
  scan_fused_k<<<B_ * (DM / SD), 256, 0, stream>>>(ab, dlt, pall, A, Dv, cw, cb, sout);
  // GEMM2: out += sout . Wout^T, split-K x2, atomic epilogue (512 blocks)
  mfma_nt<2, 2, 2, 2, 2, 2, 0, 0><<<dim3(DIN / 64, NROW / 64, 2), 256, 0, stream>>>(
      sout, Wout, nullptr, nullptr, out, nullptr, nullptr, nullptr, nullptr,
      NROW, DIN, DM, DM, DM, DIN);
}